// Round 7
// baseline (377.724 us; speedup 1.0000x reference)
//
#include <hip/hip_runtime.h>
#include <math.h>

#define NB 4
#define TT 1024
#define DD 1024
#define NTOK 4096
#define ND (NTOK*DD)

typedef __attribute__((ext_vector_type(8))) short bh8;
typedef __attribute__((ext_vector_type(4))) float fx4;

__device__ __forceinline__ unsigned short f2bf(float f) {
    unsigned int b = __float_as_uint(f);
    b += 0x7fffu + ((b >> 16) & 1u);
    return (unsigned short)(b >> 16);
}

// pack two fp32 -> packed bf16 (RNE); HW v_cvt_pk_bf16_f32 when available
__device__ __forceinline__ unsigned pkbf(float a, float b) {
#if __has_builtin(__builtin_amdgcn_cvt_pk_bf16_f32)
    auto r = __builtin_amdgcn_cvt_pk_bf16_f32(a, b);
    unsigned u;
    __builtin_memcpy(&u, &r, 4);
    return u;
#else
    return ((unsigned)f2bf(b) << 16) | f2bf(a);
#endif
}

// async global->LDS, 16B per lane, LDS dst = wave-uniform base + lane*16
#define GLD16(gp, lp) __builtin_amdgcn_global_load_lds( \
    (__attribute__((address_space(1))) void*)(gp), \
    (__attribute__((address_space(3))) void*)(lp), 16, 0, 0)

// barrier that is also a compiler memory fence
#define BARF() do { __builtin_amdgcn_s_barrier(); asm volatile("" ::: "memory"); } while (0)

// ---------- fused preprocessing: 5x wconv, w1T, dw1T, w2T ----------
__global__ __launch_bounds__(256) void k_prep(const float* __restrict__ W_r, const float* __restrict__ W_k,
                                              const float* __restrict__ W_v, const float* __restrict__ W_g,
                                              const float* __restrict__ W_o,
                                              const float* __restrict__ w1, const float* __restrict__ dw1,
                                              const float* __restrict__ w2,
                                              unsigned short* __restrict__ Wrb, unsigned short* __restrict__ Wkb,
                                              unsigned short* __restrict__ Wvb, unsigned short* __restrict__ Wgb,
                                              unsigned short* __restrict__ Wob,
                                              unsigned short* __restrict__ w1T, unsigned short* __restrict__ dw1T,
                                              unsigned short* __restrict__ w2T16) {
    int y = blockIdx.y, bx = blockIdx.x, tid = threadIdx.x;   // grid (640, 7)
    if (y < 5) {
        if (bx >= 512) return;
        const float* s = (y == 0) ? W_r : (y == 1) ? W_k : (y == 2) ? W_v : (y == 3) ? W_g : W_o;
        unsigned short* d = (y == 0) ? Wrb : (y == 1) ? Wkb : (y == 2) ? Wvb : (y == 3) ? Wgb : Wob;
        int i = (bx * 256 + tid) * 8;
        float4 a = *(const float4*)(s + i);
        float4 b = *(const float4*)(s + i + 4);
        uint4 o;
        o.x = pkbf(a.x, a.y);
        o.y = pkbf(a.z, a.w);
        o.z = pkbf(b.x, b.y);
        o.w = pkbf(b.z, b.w);
        *(uint4*)(d + i) = o;
    } else if (y == 5) {
        int o = bx * 256 + tid;          // 163840 total
        int r = o & 1023, c = o >> 10;
        w1T[o] = f2bf(w1[r * 160 + c]);
    } else {
        if (bx < 256) {
            int o = bx * 256 + tid;      // 65536 total
            int r = o & 1023, c = o >> 10;
            dw1T[o] = f2bf(dw1[r * 64 + c]);
        } else if (bx < 276) {
            int wi = bx - 256;
            int f = wi >> 2;
            int d = (wi & 3) * 256 + tid;
#pragma unroll 8
            for (int m = 0; m < 32; m++)
                w2T16[(size_t)(f * 1024 + d) * 32 + m] = f2bf(w2[(size_t)(f * 32 + m) * 1024 + d]);
        }
    }
}

// ---------- k1: xmix16 = bf16(x + dxprev * maa_x) ----------
__global__ __launch_bounds__(256) void k_mixx(const float* __restrict__ x,
                                              const float* __restrict__ maa_x,
                                              unsigned short* __restrict__ xmix16) {
    int base = (blockIdx.x * 256 + threadIdx.x) * 4;   // grid 4096
    int t = (base >> 10) & 1023;
    int d = base & 1023;
    float4 xv = *(const float4*)(x + base);
    float4 xm = (t > 0)    ? *(const float4*)(x + base - 1024) : make_float4(0, 0, 0, 0);
    float4 xp = (t < 1023) ? *(const float4*)(x + base + 1024) : make_float4(0, 0, 0, 0);
    float4 ma = *(const float4*)(maa_x + d);
    uint2 o;
    float a0 = xv.x + (0.5f * (xm.x + xp.x) - xv.x) * ma.x;
    float a1 = xv.y + (0.5f * (xm.y + xp.y) - xv.y) * ma.y;
    float a2 = xv.z + (0.5f * (xm.z + xp.z) - xv.z) * ma.z;
    float a3 = xv.w + (0.5f * (xm.w + xp.w) - xv.w) * ma.w;
    o.x = pkbf(a0, a1);
    o.y = pkbf(a2, a3);
    *(uint2*)(xmix16 + base) = o;
}

// ---------- k2: xxx16 = bf16(tanh(xmix @ w1)), 4-wave K-split ----------
__global__ __launch_bounds__(256) void k_xxx2(const unsigned short* __restrict__ xmix16,
                                              const unsigned short* __restrict__ w1T,
                                              unsigned short* __restrict__ xxx16) {
    __shared__ __align__(16) float red[4][10][64][4];   // 40 KB
    int tid = threadIdx.x;
    int lane = tid & 63, wv = tid >> 6;
    int l15 = lane & 15, qd = lane >> 4;
    int m0 = blockIdx.x * 16;    // grid 256
    fx4 acc[10];
#pragma unroll
    for (int nt = 0; nt < 10; nt++)
#pragma unroll
        for (int r = 0; r < 4; r++) acc[nt][r] = 0.f;
    int kb0 = wv * 256;
#pragma unroll 2
    for (int kb = kb0; kb < kb0 + 256; kb += 32) {
        bh8 af = *(const bh8*)(xmix16 + (size_t)(m0 + l15) * 1024 + kb + qd * 8);
#pragma unroll
        for (int nt = 0; nt < 10; nt++) {
            bh8 bf = *(const bh8*)(w1T + (size_t)(nt * 16 + l15) * 1024 + kb + qd * 8);
            acc[nt] = __builtin_amdgcn_mfma_f32_16x16x32_bf16(af, bf, acc[nt], 0, 0, 0);
        }
    }
#pragma unroll
    for (int nt = 0; nt < 10; nt++)
        *(fx4*)&red[wv][nt][lane][0] = acc[nt];
    __syncthreads();
    if (wv == 0) {
#pragma unroll
        for (int nt = 0; nt < 10; nt++) {
            fx4 s = *(const fx4*)&red[0][nt][lane][0];
            s = s + *(const fx4*)&red[1][nt][lane][0];
            s = s + *(const fx4*)&red[2][nt][lane][0];
            s = s + *(const fx4*)&red[3][nt][lane][0];
#pragma unroll
            for (int r = 0; r < 4; r++)
                xxx16[(size_t)(m0 + qd * 4 + r) * 160 + nt * 16 + l15] = f2bf(tanhf(s[r]));
        }
    }
}

// ---------- k3: fused mm-einsum (MFMA, K=32) + five mixes, no LDS ----------
__global__ __launch_bounds__(256, 2) void k_mmix(const float* __restrict__ x,
                                                 const unsigned short* __restrict__ xxx16,
                                                 const unsigned short* __restrict__ w2T16,
                                                 const float* __restrict__ maa_w,
                                                 const float* __restrict__ maa_k,
                                                 const float* __restrict__ maa_v,
                                                 const float* __restrict__ maa_r,
                                                 const float* __restrict__ maa_g,
                                                 unsigned short* __restrict__ xw16,
                                                 unsigned short* __restrict__ xk16,
                                                 unsigned short* __restrict__ xv16,
                                                 unsigned short* __restrict__ xr16,
                                                 unsigned short* __restrict__ xg16) {
    int tid = threadIdx.x;
    int w = tid >> 6, lane = tid & 63, l15 = lane & 15, qd = lane >> 4;
    int n0 = blockIdx.x * 64;               // grid (16, 32)
    int m0w = blockIdx.y * 128 + w * 32;
    const float* maap[5] = {maa_w, maa_k, maa_v, maa_r, maa_g};
    unsigned short* outp[5] = {xw16, xk16, xv16, xr16, xg16};
    float xin[8][4], dxv[8][4];
#pragma unroll
    for (int mi = 0; mi < 2; mi++)
#pragma unroll
        for (int r = 0; r < 4; r++) {
            int tok = m0w + mi * 16 + qd * 4 + r;
            int t = tok & 1023;
#pragma unroll
            for (int ni = 0; ni < 4; ni++) {
                int d = n0 + ni * 16 + l15;
                size_t idx = (size_t)tok * 1024 + d;
                float xv = x[idx];
                float xm1 = (t > 0)    ? x[idx - 1024] : 0.f;
                float xp1 = (t < 1023) ? x[idx + 1024] : 0.f;
                xin[mi * 4 + r][ni] = xv;
                dxv[mi * 4 + r][ni] = 0.5f * (xm1 + xp1) - xv;
            }
        }
#pragma unroll
    for (int f = 0; f < 5; f++) {
        bh8 af[2], bf[4];
#pragma unroll
        for (int mi = 0; mi < 2; mi++)
            af[mi] = *(const bh8*)(xxx16 + (size_t)(m0w + mi * 16 + l15) * 160 + f * 32 + qd * 8);
#pragma unroll
        for (int ni = 0; ni < 4; ni++)
            bf[ni] = *(const bh8*)(w2T16 + (size_t)(f * 1024 + n0 + ni * 16 + l15) * 32 + qd * 8);
        fx4 acc[2][4];
#pragma unroll
        for (int mi = 0; mi < 2; mi++)
#pragma unroll
            for (int ni = 0; ni < 4; ni++) {
#pragma unroll
                for (int r = 0; r < 4; r++) acc[mi][ni][r] = 0.f;
                acc[mi][ni] = __builtin_amdgcn_mfma_f32_16x16x32_bf16(af[mi], bf[ni], acc[mi][ni], 0, 0, 0);
            }
        const float* maa = maap[f];
        unsigned short* op = outp[f];
#pragma unroll
        for (int ni = 0; ni < 4; ni++) {
            float mv = maa[n0 + ni * 16 + l15];
#pragma unroll
            for (int mi = 0; mi < 2; mi++)
#pragma unroll
                for (int r = 0; r < 4; r++) {
                    float o = xin[mi * 4 + r][ni] + dxv[mi * 4 + r][ni] * (mv + acc[mi][ni][r]);
                    op[(size_t)(m0w + mi * 16 + qd * 4 + r) * 1024 + n0 + ni * 16 + l15] = f2bf(o);
                }
        }
    }
}

// ---------- decay GEMM1: dech = tanh(xw @ dw1), 4-wave K-split ----------
__global__ __launch_bounds__(256) void k_dec1m(const unsigned short* __restrict__ xw16,
                                               const unsigned short* __restrict__ dw1T,
                                               float* __restrict__ dech) {
    __shared__ __align__(16) float red[4][4][64][4];    // 16 KB
    int tid = threadIdx.x;
    int lane = tid & 63, wv = tid >> 6;
    int l15 = lane & 15, qd = lane >> 4;
    int m0 = blockIdx.x * 16;    // grid 256
    fx4 acc[4];
#pragma unroll
    for (int nt = 0; nt < 4; nt++)
#pragma unroll
        for (int r = 0; r < 4; r++) acc[nt][r] = 0.f;
    int kb0 = wv * 256;
#pragma unroll 2
    for (int kb = kb0; kb < kb0 + 256; kb += 32) {
        bh8 af = *(const bh8*)(xw16 + (size_t)(m0 + l15) * 1024 + kb + qd * 8);
#pragma unroll
        for (int nt = 0; nt < 4; nt++) {
            bh8 bf = *(const bh8*)(dw1T + (size_t)(nt * 16 + l15) * 1024 + kb + qd * 8);
            acc[nt] = __builtin_amdgcn_mfma_f32_16x16x32_bf16(af, bf, acc[nt], 0, 0, 0);
        }
    }
#pragma unroll
    for (int nt = 0; nt < 4; nt++)
        *(fx4*)&red[wv][nt][lane][0] = acc[nt];
    __syncthreads();
    if (wv == 0) {
#pragma unroll
        for (int nt = 0; nt < 4; nt++) {
            fx4 s = *(const fx4*)&red[0][nt][lane][0];
            s = s + *(const fx4*)&red[1][nt][lane][0];
            s = s + *(const fx4*)&red[2][nt][lane][0];
            s = s + *(const fx4*)&red[3][nt][lane][0];
#pragma unroll
            for (int r = 0; r < 4; r++)
                dech[(size_t)(m0 + qd * 4 + r) * 64 + nt * 16 + l15] = tanhf(s[r]);
        }
    }
}

// ---------- decay GEMM2: ew = -exp(time_decay + dech @ dw2) ----------
__global__ __launch_bounds__(256) void k_dec2(const float* __restrict__ dech,
                                              const float* __restrict__ dw2,
                                              const float* __restrict__ tdec,
                                              float* __restrict__ ew) {
    __shared__ float hl[8][64];
    int tid = threadIdx.x;
    int tok0 = blockIdx.x * 8;     // grid 512
    {
        int l = tid;        hl[l >> 6][l & 63] = dech[tok0 * 64 + l];
        l = tid + 256;      hl[l >> 6][l & 63] = dech[tok0 * 64 + l];
    }
    __syncthreads();
#pragma unroll 1
    for (int c = 0; c < 4; c++) {
        int d = c * 256 + tid;
        float acc[8] = {};
#pragma unroll 8
        for (int j = 0; j < 64; j++) {
            float wv = dw2[j * 1024 + d];
#pragma unroll
            for (int g = 0; g < 8; g++) acc[g] = fmaf(hl[g][j], wv, acc[g]);
        }
        float td = tdec[d];
#pragma unroll
        for (int g = 0; g < 8; g++) ew[(tok0 + g) * 1024 + d] = -expf(td + acc[g]);
    }
}

// ---------- scan stage 1: per-segment sums (seg = 32) ----------
__global__ __launch_bounds__(64) void k_scan1(const float* __restrict__ ew, float* __restrict__ segsum) {
    int bx = blockIdx.x;            // grid 2048 = 4b x 32seg x 16dch
    int b = bx >> 9, seg = (bx >> 4) & 31, dch = bx & 15;
    int d = dch * 64 + threadIdx.x;
    size_t base = ((size_t)(b * 1024 + seg * 32)) * 1024 + d;
    float s = 0.f;
#pragma unroll 8
    for (int t = 0; t < 32; t++) s += ew[base + (size_t)t * 1024];
    segsum[(b * 32 + seg) * 1024 + d] = s;
}

// ---------- scan stage 2+3 fused: local prefix of segsums + emit clipped cf/cb ----------
__global__ __launch_bounds__(64) void k_scan3(const float* __restrict__ ew, const float* __restrict__ segsum,
                                              float* __restrict__ cf, float* __restrict__ cb) {
    int bx = blockIdx.x;            // grid 2048
    int b = bx >> 9, seg = (bx >> 4) & 31, dch = bx & 15;
    int d = dch * 64 + threadIdx.x;
    float run = 0.f, pre = 0.f, off16 = 0.f;
#pragma unroll
    for (int s = 0; s < 32; s++) {
        float tv = segsum[(b * 32 + s) * 1024 + d];
        if (s == seg) pre = run;
        if (s == 16) off16 = run;
        run += tv;
    }
    float e512 = ew[((size_t)(b * 1024 + 512)) * 1024 + d];
    float sb = off16;           // cs[511]
    float sf = off16 + e512;    // cs[512]
    float cum = pre;
    size_t base = ((size_t)(b * 1024 + seg * 32)) * 1024 + d;
#pragma unroll 4
    for (int t = 0; t < 32; t++) {
        float prev = cum;
        cum += ew[base + (size_t)t * 1024];
        cf[base + (size_t)t * 1024] = fminf(fmaxf(cum - sf, -60.f), 60.f);
        cb[base + (size_t)t * 1024] = fminf(fmaxf(prev - sb, -60.f), 60.f);
    }
}

// ---------- QKVG: round-1 8-phase 256x256 BK=64 engine (HW-verified), now launched
// cooperatively: grid 256 x 512thr, 128KB LDS -> capacity exactly 1 block/CU, and
// cooperative co-residency FORCES 1 block per CU (kills the collision mode that made
// r1 read 68us). Per-block rate measured ~1010 TF (r1 model fit).
#define STA(dstbuf, g, kbv, Apt) GLD16(Apt + (size_t)(m0 + aBase + (g) * 32 + lr) * 1024 + (kbv) + swz, \
                                       (dstbuf) + (aBase + (g) * 32) * 64)
#define STB(dstbuf, s, kbv, Wpt) GLD16(Wpt + (size_t)(n0 + bBase + (s) * 64 + lr) * 1024 + (kbv) + swz, \
                                       (dstbuf) + (bBase + (s) * 64) * 64)

#define PHASE(mt0_, STAGE_, TAIL_) do {                                                  \
    bh8 aA0 = *(const bh8*)(sAc + arA + (mt0_) * 1024 + fc0);                            \
    bh8 aA1 = *(const bh8*)(sAc + arA + (mt0_) * 1024 + fc1);                            \
    bh8 aB0 = *(const bh8*)(sAc + arA + ((mt0_) + 1) * 1024 + fc0);                      \
    bh8 aB1 = *(const bh8*)(sAc + arA + ((mt0_) + 1) * 1024 + fc1);                      \
    STAGE_;                                                                              \
    BARF();                                                                              \
    asm volatile("s_waitcnt lgkmcnt(0)" ::: "memory");                                   \
    __builtin_amdgcn_s_setprio(1);                                                       \
    _Pragma("unroll")                                                                    \
    for (int nt = 0; nt < 4; ++nt) {                                                     \
        acc[(mt0_)][nt]     = __builtin_amdgcn_mfma_f32_16x16x32_bf16(aA0, bfr[nt][0], acc[(mt0_)][nt], 0, 0, 0);     \
        acc[(mt0_)][nt]     = __builtin_amdgcn_mfma_f32_16x16x32_bf16(aA1, bfr[nt][1], acc[(mt0_)][nt], 0, 0, 0);     \
        acc[(mt0_) + 1][nt] = __builtin_amdgcn_mfma_f32_16x16x32_bf16(aB0, bfr[nt][0], acc[(mt0_) + 1][nt], 0, 0, 0); \
        acc[(mt0_) + 1][nt] = __builtin_amdgcn_mfma_f32_16x16x32_bf16(aB1, bfr[nt][1], acc[(mt0_) + 1][nt], 0, 0, 0); \
    }                                                                                    \
    __builtin_amdgcn_s_setprio(0);                                                       \
    TAIL_;                                                                               \
    BARF();                                                                              \
} while (0)

__global__ __launch_bounds__(512, 2) void k_qkvg(const unsigned short* __restrict__ xr16,
                                                 const unsigned short* __restrict__ xk16,
                                                 const unsigned short* __restrict__ xv16,
                                                 const unsigned short* __restrict__ xg16,
                                                 const unsigned short* __restrict__ Wrb,
                                                 const unsigned short* __restrict__ Wkb,
                                                 const unsigned short* __restrict__ Wvb,
                                                 const unsigned short* __restrict__ Wgb,
                                                 unsigned short* __restrict__ qf, unsigned short* __restrict__ qb,
                                                 unsigned short* __restrict__ kf, unsigned short* __restrict__ kb,
                                                 unsigned short* __restrict__ vvt,
                                                 float* __restrict__ gg,
                                                 const float* __restrict__ cf, const float* __restrict__ cb) {
    __shared__ __align__(16) char smem[131072];
    unsigned short* sA0 = (unsigned short*)smem;             // [256][64]
    unsigned short* sB0 = (unsigned short*)(smem + 32768);
    unsigned short* sA1 = (unsigned short*)(smem + 65536);
    unsigned short* sB1 = (unsigned short*)(smem + 98304);

    // bijective XCD swizzle: XCD x gets 32 contiguous work ids = one m-half of one GEMM
    int flat = blockIdx.x;                     // grid 256
    int wk = (flat & 7) * 32 + (flat >> 3);
    int gy = wk >> 6;                          // which GEMM
    int wi = wk & 63;
    int m0 = (wi >> 2) * 256, n0 = (wi & 3) * 256;

    const unsigned short* Ap = (gy == 0) ? xr16 : (gy == 1) ? xk16 : (gy == 2) ? xv16 : xg16;
    const unsigned short* Wp = (gy == 0) ? Wrb : (gy == 1) ? Wkb : (gy == 2) ? Wvb : Wgb;

    int tid = threadIdx.x;
    int lane = tid & 63, w = tid >> 6;
    int l15 = lane & 15, qd = lane >> 4;
    int wm = w >> 2, wn = w & 3;
    int lr = lane >> 3;                              // 0..7
    int swz = ((lane & 7) ^ lr) << 3;                // pre-swizzled global src (shorts)
    int aBase = wm * 128 + (w & 3) * 8;              // wave A-row base (A-group layout)
    int bBase = w * 8;                               // wave B-row base
    int fc0 = (qd * 8) ^ ((l15 & 7) << 3);           // swizzled frag col, kk=0 (shorts)
    int fc1 = fc0 ^ 32;                              // kk=1
    int arA = (wm * 128 + l15) * 64;                 // A frag row base addr (shorts)
    int arB = (wn * 64 + l15) * 64;                  // B frag row base addr

    fx4 acc[8][4];
#pragma unroll
    for (int mt = 0; mt < 8; mt++)
#pragma unroll
        for (int nt = 0; nt < 4; nt++)
#pragma unroll
            for (int r = 0; r < 4; r++) acc[mt][nt][r] = 0.f;

    // prologue: tile0 fully, tile1 all but A-groups 2,3
#pragma unroll
    for (int g = 0; g < 4; ++g) STA(sA0, g, 0, Ap);
#pragma unroll
    for (int s = 0; s < 4; ++s) STB(sB0, s, 0, Wp);
    asm volatile("" ::: "memory");                   // keep t0 issues before t1 issues
#pragma unroll
    for (int s = 0; s < 4; ++s) STB(sB1, s, 64, Wp);
    STA(sA1, 0, 64, Ap);
    STA(sA1, 1, 64, Ap);
    asm volatile("s_waitcnt vmcnt(6)" ::: "memory"); // tile0's 8 loads landed
    BARF();

    unsigned short* sAc = sA0;
    unsigned short* sBc = sB0;
    unsigned short* sAn = sA1;
    unsigned short* sBn = sB1;

#pragma unroll 1
    for (int t = 0; t < 16; ++t) {
        int kb1 = t * 64 + 64, kb2 = t * 64 + 128;
        bh8 bfr[4][2];
#pragma unroll
        for (int nt = 0; nt < 4; ++nt) {
            bfr[nt][0] = *(const bh8*)(sBc + arB + nt * 1024 + fc0);
            bfr[nt][1] = *(const bh8*)(sBc + arB + nt * 1024 + fc1);
        }
        PHASE(0, if (t < 15) { STA(sAn, 2, kb1, Ap); STA(sAn, 3, kb1, Ap); }, );
        PHASE(2, if (t < 14) { STB(sBc, 0, kb2, Wp); STB(sBc, 1, kb2, Wp); }, );
        PHASE(4, if (t < 14) { STB(sBc, 2, kb2, Wp); STB(sBc, 3, kb2, Wp); }, );
        PHASE(6, if (t < 14) { STA(sAc, 0, kb2, Ap); STA(sAc, 1, kb2, Ap); },
                 if (t < 14) { asm volatile("s_waitcnt vmcnt(6)" ::: "memory"); }
                 else if (t == 14) { asm volatile("s_waitcnt vmcnt(0)" ::: "memory"); } );
        unsigned short* tp;
        tp = sAc; sAc = sAn; sAn = tp;
        tp = sBc; sBc = sBn; sBn = tp;
    }

    // ----- epilogues -----
    int mb = m0 + wm * 128, nb = n0 + wn * 64;
    if (gy == 3) {                       // silu -> gg (fp32)
#pragma unroll
        for (int mt = 0; mt < 8; mt++)
#pragma unroll
            for (int nt = 0; nt < 4; nt++)
#pragma unroll
                for (int r = 0; r < 4; r++) {
                    float v = acc[mt][nt][r];
                    v = v / (1.f + __expf(-v));
                    gg[(size_t)(mb + mt * 16 + qd * 4 + r) * 1024 + nb + nt * 16 + l15] = v;
                }
    } else if (gy == 2) {                // V -> transposed bf16 vvt[(b*1024+d)][t]
        __syncthreads();
        unsigned short* T = (unsigned short*)smem;   // [256][136]
        int bq = m0 >> 10, t0 = m0 & 1023;
#pragma unroll 1
        for (int h = 0; h < 2; ++h) {
            if (wm == h) {
#pragma unroll
                for (int mt = 0; mt < 8; mt++)
#pragma unroll
                    for (int nt = 0; nt < 4; nt++) {
                        int dl = wn * 64 + nt * 16 + l15;
                        int rl = mt * 16 + qd * 4;
                        uint2 pk;
                        pk.x = pkbf(acc[mt][nt][0], acc[mt][nt][1]);
                        pk.y = pkbf(acc[mt][nt][2], acc[mt][nt][3]);
                        *(uint2*)(T + dl * 136 + rl) = pk;
                    }
            }
            __syncthreads();
#pragma unroll
            for (int i = 0; i < 8; ++i) {
                int gch = i * 512 + tid;
                int d = gch >> 4, tch = gch & 15;
                uint4 vv = *(const uint4*)(T + d * 136 + tch * 8);
                *(uint4*)(vvt + (size_t)(bq * 1024 + n0 + d) * 1024 + t0 + h * 128 + tch * 8) = vv;
            }
            __syncthreads();
        }
    } else {                             // q (gy==0) / k (gy==1) exp epilogues
        unsigned short* O1 = gy ? kf : qf;
        unsigned short* O2 = gy ? kb : qb;
        float s1 = gy ? -1.f : 1.f;
#pragma unroll
        for (int mt = 0; mt < 8; mt++)
#pragma unroll
            for (int nt = 0; nt < 4; nt++)
#pragma unroll
                for (int r = 0; r < 4; r++) {
                    size_t idx = (size_t)(mb + mt * 16 + qd * 4 + r) * 1024 + nb + nt * 16 + l15;
                    float v = acc[mt][nt][r];
                    O1[idx] = f2bf(v * __expf(s1 * cf[idx]));
                    O2[idx] = f2bf(v * __expf(-s1 * cb[idx]));
                }
    }
}

// ---------- GEMM engine v5 (narrow instantiation for k_gemmo) ----------
template<int NW, int BNv>
__device__ __forceinline__ void gemm_v5(const unsigned short* __restrict__ A,
                                        const unsigned short* __restrict__ W,
                                        int m0, int n0, int mode,
                                        float* __restrict__ Cf,
                                        unsigned short* __restrict__ O1,
                                        unsigned short* __restrict__ O2,
                                        const float* __restrict__ cfp,
                                        const float* __restrict__ cbp,
                                        char* smem) {
    constexpr int AR = 128 / NW;          // A rows staged per wave
    constexpr int AG = AR / 16;           // GLD16s for A per wave
    constexpr int BR = BNv / NW;          // B rows per wave
    constexpr int BG = BR / 16;
    constexpr int LPW = AG + BG;          // loads per wave per tile
    constexpr int SLOT = (128 + BNv) * 64;   // ring slot bytes
    constexpr int WNC = BNv / 64;

    int tid = threadIdx.x;
    int lane = tid & 63, w = tid >> 6;
    int l15 = lane & 15, qd = lane >> 4;
    int wm = w / WNC, wn = w % WNC;
    int lr = lane >> 2, lb = lane & 3;
    int gblk = lb ^ ((lr >> 1) & 3);      // pre-swizzled global 16B-block
    const unsigned short* aSrc = A + (size_t)(m0 + w * AR + lr) * 1024 + gblk * 8;
    const unsigned short* bSrc = W + (size_t)(n0 + w * BR + lr) * 1024 + gblk * 8;
    int rc = (qd ^ ((l15 >> 1) & 3)) * 8; // swizzled frag col (shorts)
    int arow = (wm * 64 + l15) * 32 + rc;
    int brow = (wn * 64 + l15) * 32 + rc;

    auto stage = [&](int off, int kbv) {
        unsigned short* _sa = (unsigned short*)(smem + off);
        unsigned short* _sb = _sa + 128 * 32;
#pragma unroll
        for (int i = 0; i < AG; ++i)
            GLD16(aSrc + kbv + (size_t)i * 16 * 1024, _sa + (w * AR + i * 16) * 32);
#pragma unroll
        for (int i = 0; i < BG; ++i)
            GLD16(bSrc + kbv + (size_t)i * 16 * 1024, _sb + (w * BR + i * 16) * 32);
    };

    fx4 acc[4][4];
#pragma unroll
    for (int mt = 0; mt < 4; mt++)
#pragma unroll
        for (int nt = 0; nt < 4; nt++)
#pragma unroll
            for (int r = 0; r < 4; r++) acc[mt][nt][r] = 0.f;

    // prologue: tiles 0, 1
    stage(0, 0);
    stage(SLOT, 32);
    if constexpr (LPW == 3) asm volatile("s_waitcnt vmcnt(3)" ::: "memory");
    else                    asm volatile("s_waitcnt vmcnt(4)" ::: "memory");
    BARF();

    int oc = 0, on = SLOT, o2 = 2 * SLOT;
#pragma unroll 1
    for (int t = 0; t < 32; ++t) {
        if (t < 30) stage(o2, (t + 2) * 32);
        const unsigned short* cA = (const unsigned short*)(smem + oc);
        const unsigned short* cB = cA + 128 * 32;
        bh8 a[4], b[4];
#pragma unroll
        for (int mt = 0; mt < 4; ++mt) a[mt] = *(const bh8*)(cA + arow + mt * 512);
#pragma unroll
        for (int nt = 0; nt < 4; ++nt) b[nt] = *(const bh8*)(cB + brow + nt * 512);
        __builtin_amdgcn_s_setprio(1);
#pragma unroll
        for (int nt = 0; nt < 4; ++nt)
#pragma unroll
            for (int mt = 0; mt < 4; ++mt)
                acc[mt][nt] = __builtin_amdgcn_mfma_f32_16x16x32_bf16(a[mt], b[nt], acc[mt][nt], 0, 0, 0);
        __builtin_amdgcn_s_setprio(0);
        asm volatile("s_waitcnt lgkmcnt(0)" ::: "memory");
        if (t < 30) {
            if constexpr (LPW == 3) asm volatile("s_waitcnt vmcnt(3)" ::: "memory");
            else                    asm volatile("s_waitcnt vmcnt(4)" ::: "memory");
        } else if (t == 30) {
            asm volatile("s_waitcnt vmcnt(0)" ::: "memory");
        }
        BARF();
        int tmp = oc; oc = on; on = o2; o2 = tmp;
    }

    // ----- epilogues: per wave 64x64 at (m0 + wm*64, n0 + wn*64) -----
    int mb = m0 + wm * 64, nb = n0 + wn * 64;
    if (mode <= 1) {
#pragma unroll
        for (int mt = 0; mt < 4; mt++)
#pragma unroll
            for (int nt = 0; nt < 4; nt++)
#pragma unroll
                for (int r = 0; r < 4; r++) {
                    float v = acc[mt][nt][r];
                    if (mode == 1) v = v / (1.f + __expf(-v));
                    Cf[(size_t)(mb + mt * 16 + qd * 4 + r) * 1024 + nb + nt * 16 + l15] = v;
                }
    } else if (mode <= 3) {
        float s1 = (mode == 2) ? 1.f : -1.f;
#pragma unroll
        for (int mt = 0; mt < 4; mt++)
#pragma unroll
            for (int nt = 0; nt < 4; nt++)
#pragma unroll
                for (int r = 0; r < 4; r++) {
                    size_t idx = (size_t)(mb + mt * 16 + qd * 4 + r) * 1024 + nb + nt * 16 + l15;
                    float v = acc[mt][nt][r];
                    O1[idx] = f2bf(v * __expf(s1 * cfp[idx]));
                    O2[idx] = f2bf(v * __expf(-s1 * cbp[idx]));
                }
    } else {
        unsigned short* T = (unsigned short*)smem;
        int bq = m0 >> 10, t0 = m0 & 1023;
#pragma unroll
        for (int mt = 0; mt < 4; mt++)
#pragma unroll
            for (int nt = 0; nt < 4; nt++) {
                int dl = wn * 64 + nt * 16 + l15;
                int tl = wm * 64 + mt * 16 + qd * 4;
                uint2 pk2;
                pk2.x = pkbf(acc[mt][nt][0], acc[mt][nt][1]);
                pk2.y = pkbf(acc[mt][nt][2], acc[mt][nt][3]);
                *(uint2*)(T + dl * 136 + tl) = pk2;
            }
        asm volatile("s_waitcnt lgkmcnt(0)" ::: "memory");
        BARF();
#pragma unroll
        for (int p = 0; p < 8; ++p) {
            int idx = p * (NW * 64) + tid;
            int dd = idx >> 4, u = idx & 15;
            uint4 vv = *(const uint4*)(T + dd * 136 + u * 8);
            *(uint4*)(O1 + (size_t)(bq * 1024 + n0 + dd) * 1024 + t0 + u * 8) = vv;
        }
    }
}

__global__ __launch_bounds__(256, 3) void k_gemmo(const unsigned short* __restrict__ z16,
                                                  const unsigned short* __restrict__ Wob,
                                                  float* __restrict__ out) {
    __shared__ __align__(16) char smem[49152];
    int flat = blockIdx.x;                     // grid 256 (256 % 8 == 0)
    int wkid = (flat & 7) * 32 + (flat >> 3);
    int m0 = (wkid >> 3) * 128, n0 = (wkid & 7) * 128;
    gemm_v5<4, 128>(z16, Wob, m0, n0, 0, out, nullptr, nullptr, nullptr, nullptr, smem);
}

// ---------- attention: bidir LION, 2 j-tiles per stage round (half the barriers) ----------
__global__ __launch_bounds__(256, 2) void k_attn(const unsigned short* __restrict__ qf,
                                                 const unsigned short* __restrict__ qb,
                                                 const unsigned short* __restrict__ kf,
                                                 const unsigned short* __restrict__ kb,
                                                 const unsigned short* __restrict__ vvt,
                                                 float* __restrict__ y) {
    __shared__ __align__(16) char smem[32768];
    unsigned short* sK = (unsigned short*)smem;             // 2 tiles x 8KB
    unsigned short* sV = (unsigned short*)(smem + 16384);   // 2 tiles x 8KB
    int tid = threadIdx.x;
    int w = tid >> 6, lane = tid & 63, l15 = lane & 15, qd = lane >> 4;
    int bid = blockIdx.x;            // grid 512 = 64 bh x 8 itile, XCD-swizzled
    int bh = (bid & 7) + ((bid >> 6) << 3);
    int ib = (bid >> 3) & 7;
    int b = bh >> 4, h = bh & 15;
    int i0w = ib * 128 + w * 32;
    int bt0 = b * 1024;
    const unsigned short* vrow = vvt + (size_t)(b * 1024 + h * 64 + w * 16 + l15) * 1024 + qd * 8;
    int fmax = (i0w + 31) >> 6;
    int bmin = i0w >> 6;
    int srcA = l15 + ((lane & 16) << 1);
    int srcB = srcA + 16;
    fx4 yacc[4][2];
#pragma unroll
    for (int mt = 0; mt < 4; mt++)
#pragma unroll
        for (int nt = 0; nt < 2; nt++)
#pragma unroll
            for (int r = 0; r < 4; r++) yacc[mt][nt][r] = 0.f;

    for (int phase = 0; phase < 2; phase++) {
        const unsigned short* Q = phase ? qb : qf;
        const unsigned short* K = phase ? kb : kf;
        bh8 qfr[2][2];
#pragma unroll
        for (int nt = 0; nt < 2; nt++)
#pragma unroll
            for (int ks = 0; ks < 2; ks++)
                qfr[nt][ks] = *(const bh8*)(Q + (size_t)(bt0 + i0w + nt * 16 + l15) * 1024
                                              + h * 64 + ks * 32 + qd * 8);
        int jlo = phase == 0 ? 0 : 2 * ib;            // both ranges have EVEN length
        int jhi = phase == 0 ? 2 * ib + 1 : 15;
        const unsigned short* krow = K + (size_t)(bt0 + w * 16 + l15) * 1024 + h * 64 + qd * 8;
        for (int jt2 = jlo; jt2 <= jhi; jt2 += 2) {
            __syncthreads();
#pragma unroll
            for (int u = 0; u < 2; ++u) {
                size_t jb = (size_t)(jt2 + u) * 64;
                GLD16(krow + jb * 1024,        sK + u * 4096 + w * 512);
                GLD16(krow + jb * 1024 + 32,   sK + u * 4096 + 2048 + w * 512);
                GLD16(vrow + jb,               sV + u * 4096 + w * 512);
                GLD16(vrow + jb + 32,          sV + u * 4096 + 2048 + w * 512);
            }
            __syncthreads();   // includes vmcnt(0) drain
#pragma unroll
            for (int u = 0; u < 2; ++u) {
                int jt = jt2 + u;
                int jb = jt * 64;
                const unsigned short* bK = sK + u * 4096;
                const unsigned short* bV = sV + u * 4096;
                bool active = (phase == 0) ? (jt <= fmax) : (jt >= bmin);
                if (!active) continue;
                bool needmask = (phase == 0) ? (jb + 63 > i0w) : (i0w + 31 >= jb);
                bh8 kc[8];
#pragma unroll
                for (int fi = 0; fi < 8; fi++)
                    kc[fi] = *(const bh8*)(bK + fi * 512 + lane * 8);
                fx4 sacc[4][2];
#pragma unroll
                for (int mt = 0; mt < 4; mt++)
#pragma unroll
                    for (int nt = 0; nt < 2; nt++)
#pragma unroll
                        for (int r = 0; r < 4; r++) sacc[mt][nt][r] = 0.f;
#pragma unroll
                for (int ks = 0; ks < 2; ks++)
#pragma unroll
                    for (int mt = 0; mt < 4; mt++)
#pragma unroll
                        for (int nt = 0; nt < 2; nt++)
                            sacc[mt][nt] = __builtin_amdgcn_mfma_f32_16x16x32_bf16(kc[ks * 4 + mt], qfr[nt][ks], sacc[mt][nt], 0, 0, 0);
                uint2 pk[4][2];
#pragma unroll
                for (int mt = 0; mt < 4; mt++)
#pragma unroll
                    for (int nt = 0; nt < 2; nt++) {
                        fx4 s = sacc[mt][nt];
                        if (needmask) {
                            int ii = i0w + nt * 16 + l15;
                            int jj0 = jb + mt * 16 + qd * 4;
#pragma unroll
                            for (int r = 0; r < 4; r++) {
                                bool keep = (phase == 0) ? (ii >= jj0 + r) : (ii < jj0 + r);
                                if (!keep) s[r] = 0.f;
                            }
                        }
                        pk[mt][nt].x = pkbf(s[0], s[1]);
                        pk[mt][nt].y = pkbf(s[2], s[3]);
                    }
                bh8 vc[8];
#pragma unroll
                for (int fi = 0; fi < 8; fi++)
                    vc[fi] = *(const bh8*)(bV + fi * 512 + lane * 8);
#pragma unroll
                for (int ks2 = 0; ks2 < 2; ks2++) {
#pragma unroll
                    for (int nt = 0; nt < 2; nt++) {
                        int lox  = __shfl((int)pk[2 * ks2][nt].x,     srcA);
                        int hix  = __shfl((int)pk[2 * ks2 + 1][nt].x, srcA);
                        int loy  = __shfl((int)pk[2 * ks2][nt].y,     srcA);
                        int hiy  = __shfl((int)pk[2 * ks2 + 1][nt].y, srcA);
                        int lox2 = __shfl((int)pk[2 * ks2][nt].x,     srcB);
                        int hix2 = __shfl((int)pk[2 * ks2 + 1][nt].x, srcB);
                        int loy2 = __shfl((int)pk[2 * ks2][nt].y,     srcB);
                        int hiy2 = __shfl((int)pk[2 * ks2 + 1][nt].y, srcB);
                        union { int4 i; bh8 h; } cv;
                        cv.i.x = (qd & 2) ? hix  : lox;
                        cv.i.y = (qd & 2) ? hiy  : loy;
                        cv.i.z = (qd & 2) ? hix2 : lox2;
                        cv.i.w = (qd & 2) ? hiy2 : loy2;
#pragma unroll
                        for (int mt = 0; mt < 4; mt++)
                            yacc[mt][nt] = __builtin_amdgcn_mfma_f32_16x16x32_bf16(vc[ks2 * 4 + mt], cv.h, yacc[mt][nt], 0, 0, 0);
                    }
                }
            }
        }
    }
#pragma unroll
    for (int mt = 0; mt < 4; mt++)
#pragma unroll
        for (int nt = 0; nt < 2; nt++) {
            fx4 s = yacc[mt][nt];
            float4 o; o.x = s[0]; o.y = s[1]; o.z = s[2]; o.w = s[3];
            *(float4*)&y[(size_t)(bt0 + i0w + nt * 16 + l15) * 1024 + h * 64 + mt * 16 + qd * 4] = o;
        }
}

// ---------- groupnorm * g -> bf16 z ----------
__global__ __launch_bounds__(256) void k_gn(const float* __restrict__ y,
                                            const float* __restrict__ g,
                                            const float* __restrict__ lnw,
                                            const float* __restrict__ lnb,
                                            unsigned short* __restrict__ z16) {
    int tid = threadIdx.x;
    int lane = tid & 63;
    int wv = tid >> 6;
    int group = blockIdx.x * 4 + wv;     // grid 16384
    int tok = group >> 4, h = group & 15;
    int d = h * 64 + lane;
    size_t idx = (size_t)tok * 1024 + d;
    float val = y[idx];
    float s = val, s2 = val * val;
#pragma unroll
    for (int off = 32; off > 0; off >>= 1) {
        s  += __shfl_xor(s, off, 64);
        s2 += __shfl_xor(s2, off, 64);
    }
    float mu = s * (1.f / 64.f);
    float var = s2 * (1.f / 64.f) - mu * mu;
    float inv = rsqrtf(var + 6.4e-4f);
    float yn = (val - mu) * inv * lnw[d] + lnb[d];
    z16[idx] = f2bf(yn * g[idx]);
}

extern "C" void kernel_launch(void* const* d_in, const int* in_sizes, int n_in,
                              void* d_out, int out_size, void* d_ws, size_t ws_size,
                              hipStream_t stream) {
    const float* x     = (const float*)d_in[0];
    const float* maa_x = (const float*)d_in[1];
    const float* maa_w = (const float*)d_in[2];
    const float* maa_k = (const float*)d_in[3];
    const float* maa_v = (const float*)d_in[4];
    const float* maa_r = (const float*)d_in[5];
    const float* maa_g = (const float*)d_in[6];
    const float* w1    = (const float*)d_in[7];
    const float* w2    = (const float*)d_in[8];
    const float* tdec  = (const float*)d_in[9];
    const float* dw1   = (const float*)d_in[10];
    const float* dw2   = (const float*)d_in[11];
    const float* W_r   = (const float*)d_in[12];
    const float* W_k   = (const float*)d_in[13];
    const float* W_v   = (const float*)d_in[14];
    const float* W_g   = (const float*)d_in[15];
    const float* W_o   = (const float*)d_in[16];
    const float* lnw   = (const float*)d_in[17];
    const float* lnb   = (const float*)d_in[18];

    float* ws = (float*)d_ws;
    size_t o = 0;
    float* dech   = ws + o; o += 262144;
    float* segsum = ws + o; o += 131072;
    float* ew     = ws + o; o += 4194304;
    float* cf     = ws + o; o += 4194304;
    float* cb     = ws + o; o += 4194304;
    float* gg     = ws + o; o += 4194304;
    unsigned short* us = (unsigned short*)(ws + o);
    size_t u = 0;
    unsigned short* xmix16 = us + u; u += 4194304;
    unsigned short* xw16 = us + u; u += 4194304;
    unsigned short* xr16 = us + u; u += 4194304;   // also z16 after gemm4
    unsigned short* xk16 = us + u; u += 4194304;
    unsigned short* xv16 = us + u; u += 4194304;
    unsigned short* xg16 = us + u; u += 4194304;
    unsigned short* qf   = us + u; u += 4194304;
    unsigned short* qb   = us + u; u += 4194304;
    unsigned short* kf   = us + u; u += 4194304;
    unsigned short* kb   = us + u; u += 4194304;
    unsigned short* vvt  = us + u; u += 4194304;
    unsigned short* Wrb  = us + u; u += 1048576;
    unsigned short* Wkb  = us + u; u += 1048576;
    unsigned short* Wvb  = us + u; u += 1048576;
    unsigned short* Wgb  = us + u; u += 1048576;
    unsigned short* Wob  = us + u; u += 1048576;
    unsigned short* w1T  = us + u; u += 163840;
    unsigned short* dw1T = us + u; u += 65536;
    unsigned short* xxx16 = us + u; u += 655360;
    unsigned short* w2T16 = us + u; u += 163840;
    float* yb0 = cf;               // attention output reuses cf (dead after gemm4)
    unsigned short* z16 = xr16;    // dead after gemm4

    k_prep<<<dim3(640, 7), 256, 0, stream>>>(W_r, W_k, W_v, W_g, W_o, w1, dw1, w2,
                                             Wrb, Wkb, Wvb, Wgb, Wob, w1T, dw1T, w2T16);
    k_mixx<<<4096, 256, 0, stream>>>(x, maa_x, xmix16);
    k_xxx2<<<256, 256, 0, stream>>>(xmix16, w1T, xxx16);
    k_mmix<<<dim3(16, 32), 256, 0, stream>>>(x, xxx16, w2T16, maa_w, maa_k, maa_v, maa_r, maa_g,
                                             xw16, xk16, xv16, xr16, xg16);
    k_dec1m<<<256, 256, 0, stream>>>(xw16, dw1T, dech);
    k_dec2<<<512, 256, 0, stream>>>(dech, dw2, tdec, ew);
    k_scan1<<<2048, 64, 0, stream>>>(ew, segsum);
    k_scan3<<<2048, 64, 0, stream>>>(ew, segsum, cf, cb);
    {
        void* ka[16];
        ka[0]  = (void*)&xr16; ka[1]  = (void*)&xk16; ka[2]  = (void*)&xv16; ka[3]  = (void*)&xg16;
        ka[4]  = (void*)&Wrb;  ka[5]  = (void*)&Wkb;  ka[6]  = (void*)&Wvb;  ka[7]  = (void*)&Wgb;
        ka[8]  = (void*)&qf;   ka[9]  = (void*)&qb;   ka[10] = (void*)&kf;   ka[11] = (void*)&kb;
        ka[12] = (void*)&vvt;  ka[13] = (void*)&gg;   ka[14] = (void*)&cf;   ka[15] = (void*)&cb;
        hipLaunchCooperativeKernel((const void*)k_qkvg, dim3(256), dim3(512), ka, 0, stream);
    }
    k_attn<<<512, 256, 0, stream>>>(qf, qb, kf, kb, vvt, yb0);
    k_gn<<<16384, 256, 0, stream>>>(yb0, gg, lnw, lnb, z16);
    k_gemmo<<<256, 256, 0, stream>>>(z16, Wob, (float*)d_out);
}

// Round 8
// 337.971 us; speedup vs baseline: 1.1176x; 1.1176x over previous
//
#include <hip/hip_runtime.h>
#include <math.h>

#define NB 4
#define TT 1024
#define DD 1024
#define NTOK 4096
#define ND (NTOK*DD)

typedef __attribute__((ext_vector_type(8))) short bh8;
typedef __attribute__((ext_vector_type(4))) float fx4;

__device__ __forceinline__ unsigned short f2bf(float f) {
    unsigned int b = __float_as_uint(f);
    b += 0x7fffu + ((b >> 16) & 1u);
    return (unsigned short)(b >> 16);
}

// pack two fp32 -> packed bf16 (RNE); HW v_cvt_pk_bf16_f32 when available
__device__ __forceinline__ unsigned pkbf(float a, float b) {
#if __has_builtin(__builtin_amdgcn_cvt_pk_bf16_f32)
    auto r = __builtin_amdgcn_cvt_pk_bf16_f32(a, b);
    unsigned u;
    __builtin_memcpy(&u, &r, 4);
    return u;
#else
    return ((unsigned)f2bf(b) << 16) | f2bf(a);
#endif
}

// async global->LDS, 16B per lane, LDS dst = wave-uniform base + lane*16
#define GLD16(gp, lp) __builtin_amdgcn_global_load_lds( \
    (__attribute__((address_space(1))) void*)(gp), \
    (__attribute__((address_space(3))) void*)(lp), 16, 0, 0)

// barrier that is also a compiler memory fence
#define BARF() do { __builtin_amdgcn_s_barrier(); asm volatile("" ::: "memory"); } while (0)

// ---------- fused preprocessing: 5x wconv, w1T, dw1T, w2T ----------
__global__ __launch_bounds__(256) void k_prep(const float* __restrict__ W_r, const float* __restrict__ W_k,
                                              const float* __restrict__ W_v, const float* __restrict__ W_g,
                                              const float* __restrict__ W_o,
                                              const float* __restrict__ w1, const float* __restrict__ dw1,
                                              const float* __restrict__ w2,
                                              unsigned short* __restrict__ Wrb, unsigned short* __restrict__ Wkb,
                                              unsigned short* __restrict__ Wvb, unsigned short* __restrict__ Wgb,
                                              unsigned short* __restrict__ Wob,
                                              unsigned short* __restrict__ w1T, unsigned short* __restrict__ dw1T,
                                              unsigned short* __restrict__ w2T16) {
    int y = blockIdx.y, bx = blockIdx.x, tid = threadIdx.x;   // grid (640, 7)
    if (y < 5) {
        if (bx >= 512) return;
        const float* s = (y == 0) ? W_r : (y == 1) ? W_k : (y == 2) ? W_v : (y == 3) ? W_g : W_o;
        unsigned short* d = (y == 0) ? Wrb : (y == 1) ? Wkb : (y == 2) ? Wvb : (y == 3) ? Wgb : Wob;
        int i = (bx * 256 + tid) * 8;
        float4 a = *(const float4*)(s + i);
        float4 b = *(const float4*)(s + i + 4);
        uint4 o;
        o.x = pkbf(a.x, a.y);
        o.y = pkbf(a.z, a.w);
        o.z = pkbf(b.x, b.y);
        o.w = pkbf(b.z, b.w);
        *(uint4*)(d + i) = o;
    } else if (y == 5) {
        int o = bx * 256 + tid;          // 163840 total
        int r = o & 1023, c = o >> 10;
        w1T[o] = f2bf(w1[r * 160 + c]);
    } else {
        if (bx < 256) {
            int o = bx * 256 + tid;      // 65536 total
            int r = o & 1023, c = o >> 10;
            dw1T[o] = f2bf(dw1[r * 64 + c]);
        } else if (bx < 276) {
            int wi = bx - 256;
            int f = wi >> 2;
            int d = (wi & 3) * 256 + tid;
#pragma unroll 8
            for (int m = 0; m < 32; m++)
                w2T16[(size_t)(f * 1024 + d) * 32 + m] = f2bf(w2[(size_t)(f * 32 + m) * 1024 + d]);
        }
    }
}

// ---------- k1: xmix16 = bf16(x + dxprev * maa_x); also emit dxprev fp32 ----------
__global__ __launch_bounds__(256) void k_mixx(const float* __restrict__ x,
                                              const float* __restrict__ maa_x,
                                              unsigned short* __restrict__ xmix16,
                                              float* __restrict__ dxf) {
    int base = (blockIdx.x * 256 + threadIdx.x) * 4;   // grid 4096
    int t = (base >> 10) & 1023;
    int d = base & 1023;
    float4 xv = *(const float4*)(x + base);
    float4 xm = (t > 0)    ? *(const float4*)(x + base - 1024) : make_float4(0, 0, 0, 0);
    float4 xp = (t < 1023) ? *(const float4*)(x + base + 1024) : make_float4(0, 0, 0, 0);
    float4 ma = *(const float4*)(maa_x + d);
    float dx0 = 0.5f * (xm.x + xp.x) - xv.x;
    float dx1 = 0.5f * (xm.y + xp.y) - xv.y;
    float dx2 = 0.5f * (xm.z + xp.z) - xv.z;
    float dx3 = 0.5f * (xm.w + xp.w) - xv.w;
    uint2 o;
    o.x = pkbf(xv.x + dx0 * ma.x, xv.y + dx1 * ma.y);
    o.y = pkbf(xv.z + dx2 * ma.z, xv.w + dx3 * ma.w);
    *(uint2*)(xmix16 + base) = o;
    float4 dq; dq.x = dx0; dq.y = dx1; dq.z = dx2; dq.w = dx3;
    *(float4*)(dxf + base) = dq;
}

// ---------- k2: xxx16 = bf16(tanh(xmix @ w1)), 4-wave K-split ----------
__global__ __launch_bounds__(256) void k_xxx2(const unsigned short* __restrict__ xmix16,
                                              const unsigned short* __restrict__ w1T,
                                              unsigned short* __restrict__ xxx16) {
    __shared__ __align__(16) float red[4][10][64][4];   // 40 KB
    int tid = threadIdx.x;
    int lane = tid & 63, wv = tid >> 6;
    int l15 = lane & 15, qd = lane >> 4;
    int m0 = blockIdx.x * 16;    // grid 256
    fx4 acc[10];
#pragma unroll
    for (int nt = 0; nt < 10; nt++)
#pragma unroll
        for (int r = 0; r < 4; r++) acc[nt][r] = 0.f;
    int kb0 = wv * 256;
#pragma unroll 2
    for (int kb = kb0; kb < kb0 + 256; kb += 32) {
        bh8 af = *(const bh8*)(xmix16 + (size_t)(m0 + l15) * 1024 + kb + qd * 8);
#pragma unroll
        for (int nt = 0; nt < 10; nt++) {
            bh8 bf = *(const bh8*)(w1T + (size_t)(nt * 16 + l15) * 1024 + kb + qd * 8);
            acc[nt] = __builtin_amdgcn_mfma_f32_16x16x32_bf16(af, bf, acc[nt], 0, 0, 0);
        }
    }
#pragma unroll
    for (int nt = 0; nt < 10; nt++)
        *(fx4*)&red[wv][nt][lane][0] = acc[nt];
    __syncthreads();
    if (wv == 0) {
#pragma unroll
        for (int nt = 0; nt < 10; nt++) {
            fx4 s = *(const fx4*)&red[0][nt][lane][0];
            s = s + *(const fx4*)&red[1][nt][lane][0];
            s = s + *(const fx4*)&red[2][nt][lane][0];
            s = s + *(const fx4*)&red[3][nt][lane][0];
#pragma unroll
            for (int r = 0; r < 4; r++)
                xxx16[(size_t)(m0 + qd * 4 + r) * 160 + nt * 16 + l15] = f2bf(tanhf(s[r]));
        }
    }
}

// ---------- k3: fused mm-einsum (MFMA, K=32) + five mixes; dxprev precomputed ----------
__global__ __launch_bounds__(256, 2) void k_mmix(const float* __restrict__ x,
                                                 const float* __restrict__ dxf,
                                                 const unsigned short* __restrict__ xxx16,
                                                 const unsigned short* __restrict__ w2T16,
                                                 const float* __restrict__ maa_w,
                                                 const float* __restrict__ maa_k,
                                                 const float* __restrict__ maa_v,
                                                 const float* __restrict__ maa_r,
                                                 const float* __restrict__ maa_g,
                                                 unsigned short* __restrict__ xw16,
                                                 unsigned short* __restrict__ xk16,
                                                 unsigned short* __restrict__ xv16,
                                                 unsigned short* __restrict__ xr16,
                                                 unsigned short* __restrict__ xg16) {
    int tid = threadIdx.x;
    int w = tid >> 6, lane = tid & 63, l15 = lane & 15, qd = lane >> 4;
    int n0 = blockIdx.x * 64;               // grid (16, 32)
    int m0w = blockIdx.y * 128 + w * 32;
    const float* maap[5] = {maa_w, maa_k, maa_v, maa_r, maa_g};
    unsigned short* outp[5] = {xw16, xk16, xv16, xr16, xg16};
    float xin[8][4], dxv[8][4];
#pragma unroll
    for (int mi = 0; mi < 2; mi++)
#pragma unroll
        for (int r = 0; r < 4; r++) {
            int tok = m0w + mi * 16 + qd * 4 + r;
#pragma unroll
            for (int ni = 0; ni < 4; ni++) {
                int d = n0 + ni * 16 + l15;
                size_t idx = (size_t)tok * 1024 + d;
                xin[mi * 4 + r][ni] = x[idx];
                dxv[mi * 4 + r][ni] = dxf[idx];
            }
        }
#pragma unroll
    for (int f = 0; f < 5; f++) {
        bh8 af[2], bf[4];
#pragma unroll
        for (int mi = 0; mi < 2; mi++)
            af[mi] = *(const bh8*)(xxx16 + (size_t)(m0w + mi * 16 + l15) * 160 + f * 32 + qd * 8);
#pragma unroll
        for (int ni = 0; ni < 4; ni++)
            bf[ni] = *(const bh8*)(w2T16 + (size_t)(f * 1024 + n0 + ni * 16 + l15) * 32 + qd * 8);
        fx4 acc[2][4];
#pragma unroll
        for (int mi = 0; mi < 2; mi++)
#pragma unroll
            for (int ni = 0; ni < 4; ni++) {
#pragma unroll
                for (int r = 0; r < 4; r++) acc[mi][ni][r] = 0.f;
                acc[mi][ni] = __builtin_amdgcn_mfma_f32_16x16x32_bf16(af[mi], bf[ni], acc[mi][ni], 0, 0, 0);
            }
        const float* maa = maap[f];
        unsigned short* op = outp[f];
#pragma unroll
        for (int ni = 0; ni < 4; ni++) {
            float mv = maa[n0 + ni * 16 + l15];
#pragma unroll
            for (int mi = 0; mi < 2; mi++)
#pragma unroll
                for (int r = 0; r < 4; r++) {
                    float o = xin[mi * 4 + r][ni] + dxv[mi * 4 + r][ni] * (mv + acc[mi][ni][r]);
                    op[(size_t)(m0w + mi * 16 + qd * 4 + r) * 1024 + n0 + ni * 16 + l15] = f2bf(o);
                }
        }
    }
}

// ---------- decay GEMM1: dech = tanh(xw @ dw1), 4-wave K-split ----------
__global__ __launch_bounds__(256) void k_dec1m(const unsigned short* __restrict__ xw16,
                                               const unsigned short* __restrict__ dw1T,
                                               float* __restrict__ dech) {
    __shared__ __align__(16) float red[4][4][64][4];    // 16 KB
    int tid = threadIdx.x;
    int lane = tid & 63, wv = tid >> 6;
    int l15 = lane & 15, qd = lane >> 4;
    int m0 = blockIdx.x * 16;    // grid 256
    fx4 acc[4];
#pragma unroll
    for (int nt = 0; nt < 4; nt++)
#pragma unroll
        for (int r = 0; r < 4; r++) acc[nt][r] = 0.f;
    int kb0 = wv * 256;
#pragma unroll 2
    for (int kb = kb0; kb < kb0 + 256; kb += 32) {
        bh8 af = *(const bh8*)(xw16 + (size_t)(m0 + l15) * 1024 + kb + qd * 8);
#pragma unroll
        for (int nt = 0; nt < 4; nt++) {
            bh8 bf = *(const bh8*)(dw1T + (size_t)(nt * 16 + l15) * 1024 + kb + qd * 8);
            acc[nt] = __builtin_amdgcn_mfma_f32_16x16x32_bf16(af, bf, acc[nt], 0, 0, 0);
        }
    }
#pragma unroll
    for (int nt = 0; nt < 4; nt++)
        *(fx4*)&red[wv][nt][lane][0] = acc[nt];
    __syncthreads();
    if (wv == 0) {
#pragma unroll
        for (int nt = 0; nt < 4; nt++) {
            fx4 s = *(const fx4*)&red[0][nt][lane][0];
            s = s + *(const fx4*)&red[1][nt][lane][0];
            s = s + *(const fx4*)&red[2][nt][lane][0];
            s = s + *(const fx4*)&red[3][nt][lane][0];
#pragma unroll
            for (int r = 0; r < 4; r++)
                dech[(size_t)(m0 + qd * 4 + r) * 64 + nt * 16 + l15] = tanhf(s[r]);
        }
    }
}

// ---------- decay GEMM2: ew = -exp(time_decay + dech @ dw2) ----------
__global__ __launch_bounds__(256) void k_dec2(const float* __restrict__ dech,
                                              const float* __restrict__ dw2,
                                              const float* __restrict__ tdec,
                                              float* __restrict__ ew) {
    __shared__ float hl[8][64];
    int tid = threadIdx.x;
    int tok0 = blockIdx.x * 8;     // grid 512
    {
        int l = tid;        hl[l >> 6][l & 63] = dech[tok0 * 64 + l];
        l = tid + 256;      hl[l >> 6][l & 63] = dech[tok0 * 64 + l];
    }
    __syncthreads();
#pragma unroll 1
    for (int c = 0; c < 4; c++) {
        int d = c * 256 + tid;
        float acc[8] = {};
#pragma unroll 8
        for (int j = 0; j < 64; j++) {
            float wv = dw2[j * 1024 + d];
#pragma unroll
            for (int g = 0; g < 8; g++) acc[g] = fmaf(hl[g][j], wv, acc[g]);
        }
        float td = tdec[d];
#pragma unroll
        for (int g = 0; g < 8; g++) ew[(tok0 + g) * 1024 + d] = -expf(td + acc[g]);
    }
}

// ---------- scan stage 1: per-segment sums (seg = 32) ----------
__global__ __launch_bounds__(64) void k_scan1(const float* __restrict__ ew, float* __restrict__ segsum) {
    int bx = blockIdx.x;            // grid 2048 = 4b x 32seg x 16dch
    int b = bx >> 9, seg = (bx >> 4) & 31, dch = bx & 15;
    int d = dch * 64 + threadIdx.x;
    size_t base = ((size_t)(b * 1024 + seg * 32)) * 1024 + d;
    float s = 0.f;
#pragma unroll 8
    for (int t = 0; t < 32; t++) s += ew[base + (size_t)t * 1024];
    segsum[(b * 32 + seg) * 1024 + d] = s;
}

// ---------- scan stage 2+3 fused: local prefix of segsums + emit clipped cf/cb ----------
__global__ __launch_bounds__(64) void k_scan3(const float* __restrict__ ew, const float* __restrict__ segsum,
                                              float* __restrict__ cf, float* __restrict__ cb) {
    int bx = blockIdx.x;            // grid 2048
    int b = bx >> 9, seg = (bx >> 4) & 31, dch = bx & 15;
    int d = dch * 64 + threadIdx.x;
    float run = 0.f, pre = 0.f, off16 = 0.f;
#pragma unroll
    for (int s = 0; s < 32; s++) {
        float tv = segsum[(b * 32 + s) * 1024 + d];
        if (s == seg) pre = run;
        if (s == 16) off16 = run;
        run += tv;
    }
    float e512 = ew[((size_t)(b * 1024 + 512)) * 1024 + d];
    float sb = off16;           // cs[511]
    float sf = off16 + e512;    // cs[512]
    float cum = pre;
    size_t base = ((size_t)(b * 1024 + seg * 32)) * 1024 + d;
#pragma unroll 4
    for (int t = 0; t < 32; t++) {
        float prev = cum;
        cum += ew[base + (size_t)t * 1024];
        cf[base + (size_t)t * 1024] = fminf(fmaxf(cum - sf, -60.f), 60.f);
        cb[base + (size_t)t * 1024] = fminf(fmaxf(prev - sb, -60.f), 60.f);
    }
}

// ---------- GEMM engine v5: occupancy-first. BM=128, BN templated, BK=32 ----------
// Wide  (NW=8, BN=256): 512 thr, wave 64x64 (64 AGPR), regs forced <=128 by
//   __launch_bounds__(512,4); LDS ring-3 x 24KB = 72KB -> 2 blocks x 8 waves
//   = 16 waves/CU (4/SIMD). Per wave/tile: 16 MFMA, 8 b128, 3 GLD16 -> vmcnt(3).
// Narrow (NW=4, BN=128): 256 thr, ring-3 x 16KB = 48KB -> 3 blocks/CU (12 waves).
// Zero-conflict swizzle proven in r4: stage gblk = lb ^ ((lr>>1)&3),
// read col qd ^ ((l15>>1)&3). One barrier/tile, counted vmcnt (never 0 till tail).
// modes: 0 fp32 out, 1 silu fp32, 2 q-exp (O1=qf,O2=qb), 3 k-exp, 4 v-transpose (O1=vvt)
template<int NW, int BNv>
__device__ __forceinline__ void gemm_v5(const unsigned short* __restrict__ A,
                                        const unsigned short* __restrict__ W,
                                        int m0, int n0, int mode,
                                        float* __restrict__ Cf,
                                        unsigned short* __restrict__ O1,
                                        unsigned short* __restrict__ O2,
                                        const float* __restrict__ cfp,
                                        const float* __restrict__ cbp,
                                        char* smem) {
    constexpr int AR = 128 / NW;          // A rows staged per wave
    constexpr int AG = AR / 16;           // GLD16s for A per wave
    constexpr int BR = BNv / NW;          // B rows per wave
    constexpr int BG = BR / 16;
    constexpr int LPW = AG + BG;          // loads per wave per tile
    constexpr int SLOT = (128 + BNv) * 64;   // ring slot bytes
    constexpr int WNC = BNv / 64;

    int tid = threadIdx.x;
    int lane = tid & 63, w = tid >> 6;
    int l15 = lane & 15, qd = lane >> 4;
    int wm = w / WNC, wn = w % WNC;
    int lr = lane >> 2, lb = lane & 3;
    int gblk = lb ^ ((lr >> 1) & 3);      // pre-swizzled global 16B-block
    const unsigned short* aSrc = A + (size_t)(m0 + w * AR + lr) * 1024 + gblk * 8;
    const unsigned short* bSrc = W + (size_t)(n0 + w * BR + lr) * 1024 + gblk * 8;
    int rc = (qd ^ ((l15 >> 1) & 3)) * 8; // swizzled frag col (shorts)
    int arow = (wm * 64 + l15) * 32 + rc;
    int brow = (wn * 64 + l15) * 32 + rc;

    auto stage = [&](int off, int kbv) {
        unsigned short* _sa = (unsigned short*)(smem + off);
        unsigned short* _sb = _sa + 128 * 32;
#pragma unroll
        for (int i = 0; i < AG; ++i)
            GLD16(aSrc + kbv + (size_t)i * 16 * 1024, _sa + (w * AR + i * 16) * 32);
#pragma unroll
        for (int i = 0; i < BG; ++i)
            GLD16(bSrc + kbv + (size_t)i * 16 * 1024, _sb + (w * BR + i * 16) * 32);
    };

    fx4 acc[4][4];
#pragma unroll
    for (int mt = 0; mt < 4; mt++)
#pragma unroll
        for (int nt = 0; nt < 4; nt++)
#pragma unroll
            for (int r = 0; r < 4; r++) acc[mt][nt][r] = 0.f;

    // prologue: tiles 0, 1
    stage(0, 0);
    stage(SLOT, 32);
    if constexpr (LPW == 3) asm volatile("s_waitcnt vmcnt(3)" ::: "memory");
    else                    asm volatile("s_waitcnt vmcnt(4)" ::: "memory");
    BARF();

    int oc = 0, on = SLOT, o2 = 2 * SLOT;
#pragma unroll 1
    for (int t = 0; t < 32; ++t) {
        if (t < 30) stage(o2, (t + 2) * 32);
        const unsigned short* cA = (const unsigned short*)(smem + oc);
        const unsigned short* cB = cA + 128 * 32;
        bh8 a[4], b[4];
#pragma unroll
        for (int mt = 0; mt < 4; ++mt) a[mt] = *(const bh8*)(cA + arow + mt * 512);
#pragma unroll
        for (int nt = 0; nt < 4; ++nt) b[nt] = *(const bh8*)(cB + brow + nt * 512);
        __builtin_amdgcn_s_setprio(1);
#pragma unroll
        for (int nt = 0; nt < 4; ++nt)
#pragma unroll
            for (int mt = 0; mt < 4; ++mt)
                acc[mt][nt] = __builtin_amdgcn_mfma_f32_16x16x32_bf16(a[mt], b[nt], acc[mt][nt], 0, 0, 0);
        __builtin_amdgcn_s_setprio(0);
        asm volatile("s_waitcnt lgkmcnt(0)" ::: "memory");
        if (t < 30) {
            if constexpr (LPW == 3) asm volatile("s_waitcnt vmcnt(3)" ::: "memory");
            else                    asm volatile("s_waitcnt vmcnt(4)" ::: "memory");
        } else if (t == 30) {
            asm volatile("s_waitcnt vmcnt(0)" ::: "memory");
        }
        BARF();
        int tmp = oc; oc = on; on = o2; o2 = tmp;
    }

    // ----- epilogues: per wave 64x64 at (m0 + wm*64, n0 + wn*64) -----
    int mb = m0 + wm * 64, nb = n0 + wn * 64;
    if (mode <= 1) {
#pragma unroll
        for (int mt = 0; mt < 4; mt++)
#pragma unroll
            for (int nt = 0; nt < 4; nt++)
#pragma unroll
                for (int r = 0; r < 4; r++) {
                    float v = acc[mt][nt][r];
                    if (mode == 1) v = v / (1.f + __expf(-v));
                    Cf[(size_t)(mb + mt * 16 + qd * 4 + r) * 1024 + nb + nt * 16 + l15] = v;
                }
    } else if (mode <= 3) {
        float s1 = (mode == 2) ? 1.f : -1.f;
#pragma unroll
        for (int mt = 0; mt < 4; mt++)
#pragma unroll
            for (int nt = 0; nt < 4; nt++)
#pragma unroll
                for (int r = 0; r < 4; r++) {
                    size_t idx = (size_t)(mb + mt * 16 + qd * 4 + r) * 1024 + nb + nt * 16 + l15;
                    float v = acc[mt][nt][r];
                    O1[idx] = f2bf(v * __expf(s1 * cfp[idx]));
                    O2[idx] = f2bf(v * __expf(-s1 * cbp[idx]));
                }
    } else {
        // V transpose: vvt[(b*1024 + d)][t]; T[BNv d][136] shorts
        unsigned short* T = (unsigned short*)smem;
        int bq = m0 >> 10, t0 = m0 & 1023;
#pragma unroll
        for (int mt = 0; mt < 4; mt++)
#pragma unroll
            for (int nt = 0; nt < 4; nt++) {
                int dl = wn * 64 + nt * 16 + l15;
                int tl = wm * 64 + mt * 16 + qd * 4;
                uint2 pk2;
                pk2.x = pkbf(acc[mt][nt][0], acc[mt][nt][1]);
                pk2.y = pkbf(acc[mt][nt][2], acc[mt][nt][3]);
                *(uint2*)(T + dl * 136 + tl) = pk2;
            }
        asm volatile("s_waitcnt lgkmcnt(0)" ::: "memory");
        BARF();
#pragma unroll
        for (int p = 0; p < 8; ++p) {
            int idx = p * (NW * 64) + tid;
            int dd = idx >> 4, u = idx & 15;
            uint4 vv = *(const uint4*)(T + dd * 136 + u * 8);
            *(uint4*)(O1 + (size_t)(bq * 1024 + n0 + dd) * 1024 + t0 + u * 8) = vv;
        }
    }
}

__global__ __launch_bounds__(512, 4) void k_qkvg(const unsigned short* __restrict__ xr16,
                                                 const unsigned short* __restrict__ xk16,
                                                 const unsigned short* __restrict__ xv16,
                                                 const unsigned short* __restrict__ xg16,
                                                 const unsigned short* __restrict__ Wrb,
                                                 const unsigned short* __restrict__ Wkb,
                                                 const unsigned short* __restrict__ Wvb,
                                                 const unsigned short* __restrict__ Wgb,
                                                 unsigned short* __restrict__ qf, unsigned short* __restrict__ qb,
                                                 unsigned short* __restrict__ kf, unsigned short* __restrict__ kb,
                                                 unsigned short* __restrict__ vvt,
                                                 float* __restrict__ gg,
                                                 const float* __restrict__ cf, const float* __restrict__ cb) {
    __shared__ __align__(16) char smem[73728];
    // bijective XCD swizzle (512 % 8 == 0): XCD x gets 64 contiguous work ids
    int flat = blockIdx.x;
    int wkid = (flat & 7) * 64 + (flat >> 3);
    int gy = wkid >> 7;                        // which GEMM (128 tiles each)
    int rem = wkid & 127;
    int m0 = (rem >> 2) * 128, n0 = (rem & 3) * 256;
    const unsigned short* Ap = (gy == 0) ? xr16 : (gy == 1) ? xk16 : (gy == 2) ? xv16 : xg16;
    const unsigned short* Wp = (gy == 0) ? Wrb : (gy == 1) ? Wkb : (gy == 2) ? Wvb : Wgb;
    int mode = (gy == 0) ? 2 : (gy == 1) ? 3 : (gy == 2) ? 4 : 1;
    unsigned short* o1 = (gy == 0) ? qf : (gy == 1) ? kf : (gy == 2) ? vvt : nullptr;
    unsigned short* o2 = (gy == 0) ? qb : (gy == 1) ? kb : nullptr;
    float* cfo = (gy == 3) ? gg : nullptr;
    gemm_v5<8, 256>(Ap, Wp, m0, n0, mode, cfo, o1, o2, cf, cb, smem);
}

__global__ __launch_bounds__(256, 3) void k_gemmo(const unsigned short* __restrict__ z16,
                                                  const unsigned short* __restrict__ Wob,
                                                  float* __restrict__ out) {
    __shared__ __align__(16) char smem[49152];
    int flat = blockIdx.x;                     // grid 256 (256 % 8 == 0)
    int wkid = (flat & 7) * 32 + (flat >> 3);
    int m0 = (wkid >> 3) * 128, n0 = (wkid & 7) * 128;
    gemm_v5<4, 128>(z16, Wob, m0, n0, 0, out, nullptr, nullptr, nullptr, nullptr, smem);
}

// ---------- attention: bidir LION, 2 j-tiles per stage round (half the barriers) ----------
__global__ __launch_bounds__(256, 2) void k_attn(const unsigned short* __restrict__ qf,
                                                 const unsigned short* __restrict__ qb,
                                                 const unsigned short* __restrict__ kf,
                                                 const unsigned short* __restrict__ kb,
                                                 const unsigned short* __restrict__ vvt,
                                                 float* __restrict__ y) {
    __shared__ __align__(16) char smem[32768];
    unsigned short* sK = (unsigned short*)smem;             // 2 tiles x 8KB
    unsigned short* sV = (unsigned short*)(smem + 16384);   // 2 tiles x 8KB
    int tid = threadIdx.x;
    int w = tid >> 6, lane = tid & 63, l15 = lane & 15, qd = lane >> 4;
    int bid = blockIdx.x;            // grid 512 = 64 bh x 8 itile, XCD-swizzled
    int bh = (bid & 7) + ((bid >> 6) << 3);
    int ib = (bid >> 3) & 7;
    int b = bh >> 4, h = bh & 15;
    int i0w = ib * 128 + w * 32;
    int bt0 = b * 1024;
    const unsigned short* vrow = vvt + (size_t)(b * 1024 + h * 64 + w * 16 + l15) * 1024 + qd * 8;
    int fmax = (i0w + 31) >> 6;
    int bmin = i0w >> 6;
    int srcA = l15 + ((lane & 16) << 1);
    int srcB = srcA + 16;
    fx4 yacc[4][2];
#pragma unroll
    for (int mt = 0; mt < 4; mt++)
#pragma unroll
        for (int nt = 0; nt < 2; nt++)
#pragma unroll
            for (int r = 0; r < 4; r++) yacc[mt][nt][r] = 0.f;

    for (int phase = 0; phase < 2; phase++) {
        const unsigned short* Q = phase ? qb : qf;
        const unsigned short* K = phase ? kb : kf;
        bh8 qfr[2][2];
#pragma unroll
        for (int nt = 0; nt < 2; nt++)
#pragma unroll
            for (int ks = 0; ks < 2; ks++)
                qfr[nt][ks] = *(const bh8*)(Q + (size_t)(bt0 + i0w + nt * 16 + l15) * 1024
                                              + h * 64 + ks * 32 + qd * 8);
        int jlo = phase == 0 ? 0 : 2 * ib;            // both ranges have EVEN length
        int jhi = phase == 0 ? 2 * ib + 1 : 15;
        const unsigned short* krow = K + (size_t)(bt0 + w * 16 + l15) * 1024 + h * 64 + qd * 8;
        for (int jt2 = jlo; jt2 <= jhi; jt2 += 2) {
            __syncthreads();
#pragma unroll
            for (int u = 0; u < 2; ++u) {
                size_t jb = (size_t)(jt2 + u) * 64;
                GLD16(krow + jb * 1024,        sK + u * 4096 + w * 512);
                GLD16(krow + jb * 1024 + 32,   sK + u * 4096 + 2048 + w * 512);
                GLD16(vrow + jb,               sV + u * 4096 + w * 512);
                GLD16(vrow + jb + 32,          sV + u * 4096 + 2048 + w * 512);
            }
            __syncthreads();   // includes vmcnt(0) drain
#pragma unroll
            for (int u = 0; u < 2; ++u) {
                int jt = jt2 + u;
                int jb = jt * 64;
                const unsigned short* bK = sK + u * 4096;
                const unsigned short* bV = sV + u * 4096;
                bool active = (phase == 0) ? (jt <= fmax) : (jt >= bmin);
                if (!active) continue;
                bool needmask = (phase == 0) ? (jb + 63 > i0w) : (i0w + 31 >= jb);
                bh8 kc[8];
#pragma unroll
                for (int fi = 0; fi < 8; fi++)
                    kc[fi] = *(const bh8*)(bK + fi * 512 + lane * 8);
                fx4 sacc[4][2];
#pragma unroll
                for (int mt = 0; mt < 4; mt++)
#pragma unroll
                    for (int nt = 0; nt < 2; nt++)
#pragma unroll
                        for (int r = 0; r < 4; r++) sacc[mt][nt][r] = 0.f;
#pragma unroll
                for (int ks = 0; ks < 2; ks++)
#pragma unroll
                    for (int mt = 0; mt < 4; mt++)
#pragma unroll
                        for (int nt = 0; nt < 2; nt++)
                            sacc[mt][nt] = __builtin_amdgcn_mfma_f32_16x16x32_bf16(kc[ks * 4 + mt], qfr[nt][ks], sacc[mt][nt], 0, 0, 0);
                uint2 pk[4][2];
#pragma unroll
                for (int mt = 0; mt < 4; mt++)
#pragma unroll
                    for (int nt = 0; nt < 2; nt++) {
                        fx4 s = sacc[mt][nt];
                        if (needmask) {
                            int ii = i0w + nt * 16 + l15;
                            int jj0 = jb + mt * 16 + qd * 4;
#pragma unroll
                            for (int r = 0; r < 4; r++) {
                                bool keep = (phase == 0) ? (ii >= jj0 + r) : (ii < jj0 + r);
                                if (!keep) s[r] = 0.f;
                            }
                        }
                        pk[mt][nt].x = pkbf(s[0], s[1]);
                        pk[mt][nt].y = pkbf(s[2], s[3]);
                    }
                bh8 vc[8];
#pragma unroll
                for (int fi = 0; fi < 8; fi++)
                    vc[fi] = *(const bh8*)(bV + fi * 512 + lane * 8);
#pragma unroll
                for (int ks2 = 0; ks2 < 2; ks2++) {
#pragma unroll
                    for (int nt = 0; nt < 2; nt++) {
                        int lox  = __shfl((int)pk[2 * ks2][nt].x,     srcA);
                        int hix  = __shfl((int)pk[2 * ks2 + 1][nt].x, srcA);
                        int loy  = __shfl((int)pk[2 * ks2][nt].y,     srcA);
                        int hiy  = __shfl((int)pk[2 * ks2 + 1][nt].y, srcA);
                        int lox2 = __shfl((int)pk[2 * ks2][nt].x,     srcB);
                        int hix2 = __shfl((int)pk[2 * ks2 + 1][nt].x, srcB);
                        int loy2 = __shfl((int)pk[2 * ks2][nt].y,     srcB);
                        int hiy2 = __shfl((int)pk[2 * ks2 + 1][nt].y, srcB);
                        union { int4 i; bh8 h; } cv;
                        cv.i.x = (qd & 2) ? hix  : lox;
                        cv.i.y = (qd & 2) ? hiy  : loy;
                        cv.i.z = (qd & 2) ? hix2 : lox2;
                        cv.i.w = (qd & 2) ? hiy2 : loy2;
#pragma unroll
                        for (int mt = 0; mt < 4; mt++)
                            yacc[mt][nt] = __builtin_amdgcn_mfma_f32_16x16x32_bf16(vc[ks2 * 4 + mt], cv.h, yacc[mt][nt], 0, 0, 0);
                    }
                }
            }
        }
    }
#pragma unroll
    for (int mt = 0; mt < 4; mt++)
#pragma unroll
        for (int nt = 0; nt < 2; nt++) {
            fx4 s = yacc[mt][nt];
            float4 o; o.x = s[0]; o.y = s[1]; o.z = s[2]; o.w = s[3];
            *(float4*)&y[(size_t)(bt0 + i0w + nt * 16 + l15) * 1024 + h * 64 + mt * 16 + qd * 4] = o;
        }
}

// ---------- groupnorm * g -> bf16 z ----------
__global__ __launch_bounds__(256) void k_gn(const float* __restrict__ y,
                                            const float* __restrict__ g,
                                            const float* __restrict__ lnw,
                                            const float* __restrict__ lnb,
                                            unsigned short* __restrict__ z16) {
    int tid = threadIdx.x;
    int lane = tid & 63;
    int wv = tid >> 6;
    int group = blockIdx.x * 4 + wv;     // grid 16384
    int tok = group >> 4, h = group & 15;
    int d = h * 64 + lane;
    size_t idx = (size_t)tok * 1024 + d;
    float val = y[idx];
    float s = val, s2 = val * val;
#pragma unroll
    for (int off = 32; off > 0; off >>= 1) {
        s  += __shfl_xor(s, off, 64);
        s2 += __shfl_xor(s2, off, 64);
    }
    float mu = s * (1.f / 64.f);
    float var = s2 * (1.f / 64.f) - mu * mu;
    float inv = rsqrtf(var + 6.4e-4f);
    float yn = (val - mu) * inv * lnw[d] + lnb[d];
    z16[idx] = f2bf(yn * g[idx]);
}

extern "C" void kernel_launch(void* const* d_in, const int* in_sizes, int n_in,
                              void* d_out, int out_size, void* d_ws, size_t ws_size,
                              hipStream_t stream) {
    const float* x     = (const float*)d_in[0];
    const float* maa_x = (const float*)d_in[1];
    const float* maa_w = (const float*)d_in[2];
    const float* maa_k = (const float*)d_in[3];
    const float* maa_v = (const float*)d_in[4];
    const float* maa_r = (const float*)d_in[5];
    const float* maa_g = (const float*)d_in[6];
    const float* w1    = (const float*)d_in[7];
    const float* w2    = (const float*)d_in[8];
    const float* tdec  = (const float*)d_in[9];
    const float* dw1   = (const float*)d_in[10];
    const float* dw2   = (const float*)d_in[11];
    const float* W_r   = (const float*)d_in[12];
    const float* W_k   = (const float*)d_in[13];
    const float* W_v   = (const float*)d_in[14];
    const float* W_g   = (const float*)d_in[15];
    const float* W_o   = (const float*)d_in[16];
    const float* lnw   = (const float*)d_in[17];
    const float* lnb   = (const float*)d_in[18];

    float* ws = (float*)d_ws;
    size_t o = 0;
    float* dech   = ws + o; o += 262144;
    float* segsum = ws + o; o += 131072;
    float* ew     = ws + o; o += 4194304;
    float* cf     = ws + o; o += 4194304;
    float* cb     = ws + o; o += 4194304;
    float* gg     = ws + o; o += 4194304;
    unsigned short* us = (unsigned short*)(ws + o);
    size_t u = 0;
    unsigned short* xmix16 = us + u; u += 4194304;
    unsigned short* xw16 = us + u; u += 4194304;
    unsigned short* xr16 = us + u; u += 4194304;   // also z16 after gemm4
    unsigned short* xk16 = us + u; u += 4194304;
    unsigned short* xv16 = us + u; u += 4194304;
    unsigned short* xg16 = us + u; u += 4194304;
    unsigned short* qf   = us + u; u += 4194304;
    unsigned short* qb   = us + u; u += 4194304;
    unsigned short* kf   = us + u; u += 4194304;
    unsigned short* kb   = us + u; u += 4194304;
    unsigned short* vvt  = us + u; u += 4194304;
    unsigned short* Wrb  = us + u; u += 1048576;
    unsigned short* Wkb  = us + u; u += 1048576;
    unsigned short* Wvb  = us + u; u += 1048576;
    unsigned short* Wgb  = us + u; u += 1048576;
    unsigned short* Wob  = us + u; u += 1048576;
    unsigned short* w1T  = us + u; u += 163840;
    unsigned short* dw1T = us + u; u += 65536;
    unsigned short* xxx16 = us + u; u += 655360;
    unsigned short* w2T16 = us + u; u += 163840;
    float* yb0 = cf;               // attention output reuses cf (dead after gemm4)
    unsigned short* z16 = xr16;    // dead after gemm4
    float* dxf = gg;               // dxprev staging: gg is dead until k_qkvg writes it

    k_prep<<<dim3(640, 7), 256, 0, stream>>>(W_r, W_k, W_v, W_g, W_o, w1, dw1, w2,
                                             Wrb, Wkb, Wvb, Wgb, Wob, w1T, dw1T, w2T16);
    k_mixx<<<4096, 256, 0, stream>>>(x, maa_x, xmix16, dxf);
    k_xxx2<<<256, 256, 0, stream>>>(xmix16, w1T, xxx16);
    k_mmix<<<dim3(16, 32), 256, 0, stream>>>(x, dxf, xxx16, w2T16, maa_w, maa_k, maa_v, maa_r, maa_g,
                                             xw16, xk16, xv16, xr16, xg16);
    k_dec1m<<<256, 256, 0, stream>>>(xw16, dw1T, dech);
    k_dec2<<<512, 256, 0, stream>>>(dech, dw2, tdec, ew);
    k_scan1<<<2048, 64, 0, stream>>>(ew, segsum);
    k_scan3<<<2048, 64, 0, stream>>>(ew, segsum, cf, cb);
    k_qkvg<<<dim3(512), dim3(512), 0, stream>>>(xr16, xk16, xv16, xg16, Wrb, Wkb, Wvb, Wgb,
                                                qf, qb, kf, kb, vvt, gg, cf, cb);
    k_attn<<<512, 256, 0, stream>>>(qf, qb, kf, kb, vvt, yb0);
    k_gn<<<16384, 256, 0, stream>>>(yb0, gg, lnw, lnb, z16);
    k_gemmo<<<256, 256, 0, stream>>>(z16, Wob, (float*)d_out);
}